// Round 3
// baseline (389.057 us; speedup 1.0000x reference)
//
#include <hip/hip_runtime.h>
#include <math.h>

#define N 64
#define S 64
#define C 128
#define P 32
#define KCLS 1000
#define HPG 24
#define C3 384
#define NS 4096   /* N*S */
#define EPSV 1e-5f

// ---- workspace layout (float offsets) ----
#define WS_XT   0                              // [P][C3][NS]      50331648
#define WS_H    (WS_XT + P*C3*NS)              // [P][HPG][NS]      3145728
#define WS_W1T  (WS_H + P*HPG*NS)              // [P][C3][HPG]       294912
#define WS_BNP  (WS_W1T + P*C3*HPG)            // [P*HPG][16][2]      24576
#define WS_BNSS (WS_BNP + P*HPG*16*2)          // [P*HPG][2]           1536
#define WS_Y    (WS_BNSS + P*HPG*2)            // [P][N][C3]         786432
#define WS_Z    (WS_Y + P*N*C3)                // [P][N]               2048
#define WS_PF   (WS_Z + P*N)                   // [P][C][N]          262144
#define WS_SC   (WS_PF + P*C*N)                // score [N][P][S]    131072

// ============ K0: transpose t_{f,s,l}[n,s,c,p] -> xT[p][i][n*S+s] ============
__global__ __launch_bounds__(256) void k0_transpose(
    const float* __restrict__ tf, const float* __restrict__ ts,
    const float* __restrict__ tl, float* __restrict__ xT)
{
  int cchunk = blockIdx.x;      // 0..31 (4 c each)
  int n = blockIdx.y;           // 0..63
  int z = blockIdx.z;           // 0..2
  const float* src = (z == 0) ? tf : (z == 1) ? ts : tl;
  int c0 = cchunk * 4;
  __shared__ float xls[4][64][33];
  int t = threadIdx.x;
  const float* base = src + (size_t)n * S * C * P;
  #pragma unroll
  for (int j = 0; j < 32; ++j) {
    int e = t + 256 * j;
    int p  = e & 31;
    int cc = (e >> 5) & 3;
    int s  = e >> 7;
    xls[cc][s][p] = base[s * C * P + (c0 + cc) * P + p];
  }
  __syncthreads();
  #pragma unroll
  for (int j = 0; j < 32; ++j) {
    int e = t + 256 * j;
    int s  = e & 63;
    int cc = (e >> 6) & 3;
    int p  = e >> 8;
    int i = z * C + c0 + cc;
    xT[(size_t)(p * C3 + i) * NS + n * S + s] = xls[cc][s][p];
  }
}

// ============ K0b: w1[p][o][i] -> w1T[p][i][o] ============
__global__ __launch_bounds__(256) void k0b_w1t(
    const float* __restrict__ w1, float* __restrict__ w1T)
{
  int p = blockIdx.x;
  int t = threadIdx.x;
  for (int e = t; e < HPG * C3; e += 256) {
    int o = e / C3, i = e % C3;
    w1T[p * HPG * C3 + i * HPG + o] = w1[p * HPG * C3 + e];
  }
}

// ============ K1: h[p][o][ns] = sum_i w1T[p][i][o] * xT[p][i][ns]; BN partials ============
__global__ __launch_bounds__(256) void k1_h(
    const float* __restrict__ xT, const float* __restrict__ w1T,
    float* __restrict__ h, float* __restrict__ bnpart)
{
  int nst = blockIdx.x;  // 0..15
  int p   = blockIdx.y;  // 0..31
  int t = threadIdx.x;
  int ns = nst * 256 + t;
  const float* xcol = xT + (size_t)p * C3 * NS + ns;
  const float* w1p  = w1T + p * C3 * HPG;
  float acc[HPG];
  #pragma unroll
  for (int o = 0; o < HPG; ++o) acc[o] = 0.f;
  // deep load batches: 16 loads in flight per wave to cover HBM latency
  for (int ib = 0; ib < C3 / 16; ++ib) {
    float xv[16];
    #pragma unroll
    for (int u = 0; u < 16; ++u)
      xv[u] = xcol[(size_t)(ib * 16 + u) * NS];
    #pragma unroll
    for (int u = 0; u < 16; ++u) {
      const float* wrow = w1p + (ib * 16 + u) * HPG;  // wave-uniform -> scalar
      #pragma unroll
      for (int o = 0; o < HPG; ++o) acc[o] += xv[u] * wrow[o];
    }
  }
  float* hp = h + (size_t)p * HPG * NS + ns;
  #pragma unroll
  for (int o = 0; o < HPG; ++o) hp[o * NS] = acc[o];
  // BN partial sums (sum, sumsq) over this block's 256 ns
  __shared__ float wred[4][HPG][2];
  int w = t >> 6, l = t & 63;
  #pragma unroll
  for (int o = 0; o < HPG; ++o) {
    float s = acc[o], q = acc[o] * acc[o];
    #pragma unroll
    for (int m = 1; m < 64; m <<= 1) {
      s += __shfl_xor(s, m, 64);
      q += __shfl_xor(q, m, 64);
    }
    if (l == 0) { wred[w][o][0] = s; wred[w][o][1] = q; }
  }
  __syncthreads();
  if (t < HPG) {
    float s = wred[0][t][0] + wred[1][t][0] + wred[2][t][0] + wred[3][t][0];
    float q = wred[0][t][1] + wred[1][t][1] + wred[2][t][1] + wred[3][t][1];
    bnpart[((p * HPG + t) * 16 + nst) * 2 + 0] = s;
    bnpart[((p * HPG + t) * 16 + nst) * 2 + 1] = q;
  }
}

// ============ K2: finalize BN1 scale/shift ============
__global__ void k2_bnstat(const float* __restrict__ bnpart,
    const float* __restrict__ g, const float* __restrict__ b,
    float* __restrict__ bnss)
{
  int t = threadIdx.x;  // 768 threads = P*HPG
  if (t >= P * HPG) return;
  float sum = 0.f, sq = 0.f;
  #pragma unroll
  for (int j = 0; j < 16; ++j) {
    sum += bnpart[t * 32 + j * 2];
    sq  += bnpart[t * 32 + j * 2 + 1];
  }
  float mu  = sum / (float)NS;
  float var = sq / (float)NS - mu * mu;
  float sc = g[t] * rsqrtf(var + EPSV);
  bnss[t * 2]     = sc;
  bnss[t * 2 + 1] = b[t] - mu * sc;
}

// ============ K3a: score[n][p][s], Z, argmax, selected gather ============
// grid (N, 8 p-chunks), block 256 = 4 waves; wave -> one p; lane = s
__global__ __launch_bounds__(256) void k3a_score(
    const float* __restrict__ h, const float* __restrict__ bnss,
    const float* __restrict__ w2, const float* __restrict__ tf,
    float* __restrict__ score, float* __restrict__ z,
    float* __restrict__ out_spf)
{
  int n = blockIdx.x;
  int p = blockIdx.y * 4 + (threadIdx.x >> 6);
  int l = threadIdx.x & 63;   // = s
  float ssum = 0.f;
  const float* hp = h + (size_t)p * HPG * NS + n * S;
  #pragma unroll
  for (int o = 0; o < HPG; ++o) {
    float hv = hp[(size_t)o * NS + l];
    float sc = bnss[(p * HPG + o) * 2];
    float sh = bnss[(p * HPG + o) * 2 + 1];
    float v = hv * sc + sh;
    v = (v >= 0.f) ? v : 0.01f * v;
    ssum += w2[p * HPG + o] * v;
  }
  float scr = 1.f / (1.f + expf(-ssum));
  // Z and first-max argmax (all lanes converge via butterfly)
  float zs = scr;
  #pragma unroll
  for (int m = 1; m < 64; m <<= 1) zs += __shfl_xor(zs, m, 64);
  float mv = scr; int mi = l;
  #pragma unroll
  for (int m = 1; m < 64; m <<= 1) {
    float ov = __shfl_xor(mv, m, 64);
    int   oi = __shfl_xor(mi, m, 64);
    if (ov > mv || (ov == mv && oi < mi)) { mv = ov; mi = oi; }
  }
  if (l == 0) z[p * N + n] = zs;
  score[((size_t)n * P + p) * S + l] = scr;
  // selected_part_feature[p][n][c] = t_f[n, mi, c, p]
  #pragma unroll
  for (int cc = 0; cc < 2; ++cc) {
    int c = l + cc * 64;
    float v = tf[(size_t)n * S * C * P + (size_t)mi * C * P + c * P + p];
    out_spf[((size_t)p * N + n) * C + c] = v;
  }
}

// ============ K3b: y[p][n][i] = sum_s xT[p][i][ns] * score[n][p][s] ============
// grid (N, 16 i-chunks of 24), block 256: p = t>>3, il = t&7 (3 i each)
__global__ __launch_bounds__(256) void k3b_y(
    const float* __restrict__ xT, const float* __restrict__ score,
    float* __restrict__ y)
{
  int n = blockIdx.x, ic = blockIdx.y;
  int t = threadIdx.x;
  int p = t >> 3, il = t & 7;
  __shared__ float sc_lds[P * S];   // [p][swizzled s], 8 KB
  // stage scores for this n: swizzle 16B chunk index by p to avoid bank conflicts
  #pragma unroll
  for (int j = 0; j < 8; ++j) {
    int e = t + 256 * j;
    int p2 = e >> 6, s2 = e & 63;
    float val = score[((size_t)n * P + p2) * S + s2];
    int phys = (s2 >> 2) ^ (p2 & 15);
    sc_lds[p2 * 64 + phys * 4 + (s2 & 3)] = val;
  }
  __syncthreads();
  int i0 = ic * 24 + il * 3;
  const float4* x0 = (const float4*)(xT + ((size_t)(p * C3 + i0    )) * NS + n * S);
  const float4* x1 = (const float4*)(xT + ((size_t)(p * C3 + i0 + 1)) * NS + n * S);
  const float4* x2 = (const float4*)(xT + ((size_t)(p * C3 + i0 + 2)) * NS + n * S);
  float a0 = 0.f, a1 = 0.f, a2 = 0.f;
  #pragma unroll
  for (int q4 = 0; q4 < 16; ++q4) {
    int phys = q4 ^ (p & 15);
    float4 sv = *(const float4*)&sc_lds[p * 64 + phys * 4];
    float4 xa = x0[q4], xb = x1[q4], xc = x2[q4];
    a0 += xa.x * sv.x + xa.y * sv.y + xa.z * sv.z + xa.w * sv.w;
    a1 += xb.x * sv.x + xb.y * sv.y + xb.z * sv.z + xb.w * sv.w;
    a2 += xc.x * sv.x + xc.y * sv.y + xc.z * sv.z + xc.w * sv.w;
  }
  float* yp = y + ((size_t)p * N + n) * C3 + i0;
  yp[0] = a0; yp[1] = a1; yp[2] = a2;
}

// ============ K4: wpv = (wd . y)/Z, BN over n, write wpv + pf[p][c][n] ============
// grid (P, 8): block = 16 c x all 64 n.  thread: n = t&63, cg = t>>6 (4 c each)
__global__ __launch_bounds__(256) void k4_wpv(
    const float* __restrict__ y, const float* __restrict__ z,
    const float* __restrict__ wd, const float* __restrict__ g,
    const float* __restrict__ b, float* __restrict__ out_wpv,
    float* __restrict__ pf)
{
  int p   = blockIdx.x;
  int cch = blockIdx.y;             // 0..7
  int t = threadIdx.x;
  int n = t & 63, cg = t >> 6;
  int cbase = cch * 16 + cg * 4;
  __shared__ float ych[96][66];     // i-major, stride 66 -> 2-way (free)
  float acc[4] = {0.f, 0.f, 0.f, 0.f};
  const float* yp  = y  + (size_t)p * N * C3;
  const float* wdp = wd + (size_t)p * C * C3;
  for (int ch = 0; ch < 4; ++ch) {
    __syncthreads();
    #pragma unroll
    for (int j = 0; j < 24; ++j) {
      int e = t + 256 * j;
      int i = e % 96, nn = e / 96;
      ych[i][nn] = yp[nn * C3 + ch * 96 + i];
    }
    __syncthreads();
    #pragma unroll
    for (int sub = 0; sub < 4; ++sub) {
      float yr[24];
      #pragma unroll
      for (int kk = 0; kk < 24; ++kk) yr[kk] = ych[sub * 24 + kk][n];
      int ibase = ch * 96 + sub * 24;
      #pragma unroll
      for (int cl = 0; cl < 4; ++cl) {
        const float4* w4 = (const float4*)(wdp + (size_t)(cbase + cl) * C3 + ibase);
        float a = 0.f;
        #pragma unroll
        for (int q = 0; q < 6; ++q) {
          float4 wv = w4[q];
          a += yr[q*4+0] * wv.x + yr[q*4+1] * wv.y
             + yr[q*4+2] * wv.z + yr[q*4+3] * wv.w;
        }
        acc[cl] += a;
      }
    }
  }
  float zinv = 1.f / z[p * N + n];
  #pragma unroll
  for (int cl = 0; cl < 4; ++cl) acc[cl] *= zinv;
  // BN over n (wave lanes are exactly n=0..63 for fixed cg)
  #pragma unroll
  for (int cl = 0; cl < 4; ++cl) {
    float v = acc[cl];
    float s = v, q = v * v;
    #pragma unroll
    for (int m = 1; m < 64; m <<= 1) {
      s += __shfl_xor(s, m, 64);
      q += __shfl_xor(q, m, 64);
    }
    float mu  = s * (1.f / 64.f);
    float var = q * (1.f / 64.f) - mu * mu;
    int c = cbase + cl;
    float sc = g[p * C + c] * rsqrtf(var + EPSV);
    float sh = b[p * C + c] - mu * sc;
    pf[((size_t)p * C + c) * N + n] = v * sc + sh;   // coalesced over n
  }
  float4 wout = make_float4(acc[0], acc[1], acc[2], acc[3]);
  *(float4*)(out_wpv + ((size_t)p * N + n) * C + cbase) = wout;
}

// ============ K5: part_classification[p][n][k] = sum_c pf[p][c][n]*fc[c][k] ============
// grid (4 kt, P, 4 n-chunks), block 256: thread = one k, 16 n
__global__ __launch_bounds__(256) void k5_fc(
    const float* __restrict__ pf, const float* __restrict__ fc,
    float* __restrict__ out0)
{
  int kt = blockIdx.x;   // 0..3
  int p  = blockIdx.y;
  int n0 = blockIdx.z * 16;
  int t = threadIdx.x;
  int k = kt * 256 + t;
  bool ok = k < KCLS;
  int kk = ok ? k : (KCLS - 1);
  float acc[16];
  #pragma unroll
  for (int j = 0; j < 16; ++j) acc[j] = 0.f;
  for (int c = 0; c < C; ++c) {
    float fv = fc[c * KCLS + kk];
    const float4* row4 = (const float4*)(pf + ((size_t)p * C + c) * N + n0);
    #pragma unroll
    for (int j4 = 0; j4 < 4; ++j4) {
      float4 r = row4[j4];   // wave-uniform -> scalar loads
      acc[j4*4+0] += r.x * fv; acc[j4*4+1] += r.y * fv;
      acc[j4*4+2] += r.z * fv; acc[j4*4+3] += r.w * fv;
    }
  }
  if (ok) {
    #pragma unroll 4
    for (int j = 0; j < 16; ++j)
      out0[(size_t)(p * N + n0 + j) * KCLS + k] = acc[j];
  }
}

extern "C" void kernel_launch(void* const* d_in, const int* in_sizes, int n_in,
                              void* d_out, int out_size, void* d_ws, size_t ws_size,
                              hipStream_t stream)
{
  const float* tf = (const float*)d_in[0];
  const float* ts = (const float*)d_in[1];
  const float* tl = (const float*)d_in[2];
  const float* w1 = (const float*)d_in[3];
  const float* g1 = (const float*)d_in[4];
  const float* b1 = (const float*)d_in[5];
  const float* w2 = (const float*)d_in[6];
  const float* wd = (const float*)d_in[7];
  const float* g  = (const float*)d_in[8];
  const float* b  = (const float*)d_in[9];
  const float* fc = (const float*)d_in[10];

  float* ws   = (float*)d_ws;
  float* xT   = ws + WS_XT;
  float* h    = ws + WS_H;
  float* w1T  = ws + WS_W1T;
  float* bnp  = ws + WS_BNP;
  float* bnss = ws + WS_BNSS;
  float* y    = ws + WS_Y;
  float* z    = ws + WS_Z;
  float* pf   = ws + WS_PF;
  float* sc   = ws + WS_SC;

  float* out0 = (float*)d_out;         // part_classification (P,N,K)
  float* out1 = out0 + P * N * KCLS;   // weighted_part_vector (P,N,C)
  float* out2 = out1 + P * N * C;      // selected_part_feature (P,N,C)

  k0_transpose<<<dim3(32, 64, 3), 256, 0, stream>>>(tf, ts, tl, xT);
  k0b_w1t<<<32, 256, 0, stream>>>(w1, w1T);
  k1_h<<<dim3(16, 32), 256, 0, stream>>>(xT, w1T, h, bnp);
  k2_bnstat<<<1, 768, 0, stream>>>(bnp, g1, b1, bnss);
  k3a_score<<<dim3(64, 8), 256, 0, stream>>>(h, bnss, w2, tf, sc, z, out2);
  k3b_y<<<dim3(64, 16), 256, 0, stream>>>(xT, sc, y);
  k4_wpv<<<dim3(32, 8), 256, 0, stream>>>(y, z, wd, g, b, out1, pf);
  k5_fc<<<dim3(4, 32, 4), 256, 0, stream>>>(pf, fc, out0);
}

// Round 4
// 287.056 us; speedup vs baseline: 1.3553x; 1.3553x over previous
//
#include <hip/hip_runtime.h>
#include <math.h>

#define N 64
#define S 64
#define C 128
#define P 32
#define KCLS 1000
#define HPG 24
#define C3 384
#define NS 4096   /* N*S */
#define EPSV 1e-5f

// ---- workspace layout (float offsets) ----
#define WS_XT   0                              // [P][C3][NS]      50331648
#define WS_H    (WS_XT + P*C3*NS)              // [P][HPG][NS]      3145728
#define WS_W1T  (WS_H + P*HPG*NS)              // [P][C3][HPG]       294912
#define WS_BNP  (WS_W1T + P*C3*HPG)            // [P*HPG][16][2]      24576
#define WS_BNSS (WS_BNP + P*HPG*16*2)          // [P*HPG][2]           1536
#define WS_Y    (WS_BNSS + P*HPG*2)            // [P][N][C3]         786432
#define WS_Z    (WS_Y + P*N*C3)                // [P][N]               2048
#define WS_PF   (WS_Z + P*N)                   // [P][C][N]          262144
#define WS_SC   (WS_PF + P*C*N)                // score [N][P][S]    131072
#define WS_MI   (WS_SC + N*P*S)                // argmax [N][P]        2048

// ============ K0: transpose t_{f,s,l}[n,s,c,p] -> xT[p][i][n*S+s] ============
__global__ __launch_bounds__(256) void k0_transpose(
    const float* __restrict__ tf, const float* __restrict__ ts,
    const float* __restrict__ tl, float* __restrict__ xT)
{
  int cchunk = blockIdx.x;      // 0..31 (4 c each)
  int n = blockIdx.y;           // 0..63
  int z = blockIdx.z;           // 0..2
  const float* src = (z == 0) ? tf : (z == 1) ? ts : tl;
  int c0 = cchunk * 4;
  __shared__ float xls[4][64][33];
  int t = threadIdx.x;
  const float* base = src + (size_t)n * S * C * P;
  #pragma unroll
  for (int j = 0; j < 32; ++j) {
    int e = t + 256 * j;
    int p  = e & 31;
    int cc = (e >> 5) & 3;
    int s  = e >> 7;
    xls[cc][s][p] = base[s * C * P + (c0 + cc) * P + p];
  }
  __syncthreads();
  #pragma unroll
  for (int j = 0; j < 32; ++j) {
    int e = t + 256 * j;
    int s  = e & 63;
    int cc = (e >> 6) & 3;
    int p  = e >> 8;
    int i = z * C + c0 + cc;
    xT[(size_t)(p * C3 + i) * NS + n * S + s] = xls[cc][s][p];
  }
}

// ============ K0b: w1[p][o][i] -> w1T[p][i][o] ============
__global__ __launch_bounds__(256) void k0b_w1t(
    const float* __restrict__ w1, float* __restrict__ w1T)
{
  int p = blockIdx.x;
  int t = threadIdx.x;
  for (int e = t; e < HPG * C3; e += 256) {
    int o = e / C3, i = e % C3;
    w1T[p * HPG * C3 + i * HPG + o] = w1[p * HPG * C3 + e];
  }
}

// ============ K1: h[p][o][ns] = sum_i w1T[p][i][o] * xT[p][i][ns]; BN partials ============
__global__ __launch_bounds__(256) void k1_h(
    const float* __restrict__ xT, const float* __restrict__ w1T,
    float* __restrict__ h, float* __restrict__ bnpart)
{
  int nst = blockIdx.x;  // 0..15
  int p   = blockIdx.y;  // 0..31
  int t = threadIdx.x;
  int ns = nst * 256 + t;
  const float* xcol = xT + (size_t)p * C3 * NS + ns;
  const float* w1p  = w1T + p * C3 * HPG;
  float acc[HPG];
  #pragma unroll
  for (int o = 0; o < HPG; ++o) acc[o] = 0.f;
  // deep load batches: 16 loads in flight per wave to cover HBM latency
  for (int ib = 0; ib < C3 / 16; ++ib) {
    float xv[16];
    #pragma unroll
    for (int u = 0; u < 16; ++u)
      xv[u] = xcol[(size_t)(ib * 16 + u) * NS];
    #pragma unroll
    for (int u = 0; u < 16; ++u) {
      const float* wrow = w1p + (ib * 16 + u) * HPG;  // wave-uniform -> scalar
      #pragma unroll
      for (int o = 0; o < HPG; ++o) acc[o] += xv[u] * wrow[o];
    }
  }
  float* hp = h + (size_t)p * HPG * NS + ns;
  #pragma unroll
  for (int o = 0; o < HPG; ++o) hp[o * NS] = acc[o];
  // BN partial sums (sum, sumsq) over this block's 256 ns
  __shared__ float wred[4][HPG][2];
  int w = t >> 6, l = t & 63;
  #pragma unroll
  for (int o = 0; o < HPG; ++o) {
    float s = acc[o], q = acc[o] * acc[o];
    #pragma unroll
    for (int m = 1; m < 64; m <<= 1) {
      s += __shfl_xor(s, m, 64);
      q += __shfl_xor(q, m, 64);
    }
    if (l == 0) { wred[w][o][0] = s; wred[w][o][1] = q; }
  }
  __syncthreads();
  if (t < HPG) {
    float s = wred[0][t][0] + wred[1][t][0] + wred[2][t][0] + wred[3][t][0];
    float q = wred[0][t][1] + wred[1][t][1] + wred[2][t][1] + wred[3][t][1];
    bnpart[((p * HPG + t) * 16 + nst) * 2 + 0] = s;
    bnpart[((p * HPG + t) * 16 + nst) * 2 + 1] = q;
  }
}

// ============ K2: finalize BN1 scale/shift ============
__global__ void k2_bnstat(const float* __restrict__ bnpart,
    const float* __restrict__ g, const float* __restrict__ b,
    float* __restrict__ bnss)
{
  int t = threadIdx.x;  // 768 threads = P*HPG
  if (t >= P * HPG) return;
  float sum = 0.f, sq = 0.f;
  #pragma unroll
  for (int j = 0; j < 16; ++j) {
    sum += bnpart[t * 32 + j * 2];
    sq  += bnpart[t * 32 + j * 2 + 1];
  }
  float mu  = sum / (float)NS;
  float var = sq / (float)NS - mu * mu;
  float sc = g[t] * rsqrtf(var + EPSV);
  bnss[t * 2]     = sc;
  bnss[t * 2 + 1] = b[t] - mu * sc;
}

// ============ K3a: score[n][p][s], Z, argmax index ============
// grid (N, 8 p-chunks), block 256 = 4 waves; wave -> one p; lane = s
__global__ __launch_bounds__(256) void k3a_score(
    const float* __restrict__ h, const float* __restrict__ bnss,
    const float* __restrict__ w2,
    float* __restrict__ score, float* __restrict__ z,
    int* __restrict__ mi_out)
{
  int n = blockIdx.x;
  int p = blockIdx.y * 4 + (threadIdx.x >> 6);
  int l = threadIdx.x & 63;   // = s
  float ssum = 0.f;
  const float* hp = h + (size_t)p * HPG * NS + n * S;
  #pragma unroll
  for (int o = 0; o < HPG; ++o) {
    float hv = hp[(size_t)o * NS + l];
    float sc = bnss[(p * HPG + o) * 2];
    float sh = bnss[(p * HPG + o) * 2 + 1];
    float v = hv * sc + sh;
    v = (v >= 0.f) ? v : 0.01f * v;
    ssum += w2[p * HPG + o] * v;
  }
  float scr = 1.f / (1.f + expf(-ssum));
  // Z and first-max argmax (all lanes converge via butterfly)
  float zs = scr;
  #pragma unroll
  for (int m = 1; m < 64; m <<= 1) zs += __shfl_xor(zs, m, 64);
  float mv = scr; int mi = l;
  #pragma unroll
  for (int m = 1; m < 64; m <<= 1) {
    float ov = __shfl_xor(mv, m, 64);
    int   oi = __shfl_xor(mi, m, 64);
    if (ov > mv || (ov == mv && oi < mi)) { mv = ov; mi = oi; }
  }
  if (l == 0) { z[p * N + n] = zs; mi_out[n * P + p] = mi; }
  score[((size_t)n * P + p) * S + l] = scr;
}

// ============ K3b: y[p][n][i] = sum_s x[n,s,i,p]*score[n,p,s], from RAW input ====
// also grabs selected = x[n, mi[p], c, p] (z==0 chunks) while streaming s.
// grid (N, 12): chunk -> z = chunk>>2, c0 = (chunk&3)*32.
// block 256: p = t&31, cl = t>>5; thread covers c = c0+cl+8j, j=0..3.
__global__ __launch_bounds__(256) void k3b_y(
    const float* __restrict__ tf, const float* __restrict__ ts,
    const float* __restrict__ tl, const float* __restrict__ score,
    const int* __restrict__ mi, float* __restrict__ y,
    float* __restrict__ out_spf)
{
  int n = blockIdx.x, chunk = blockIdx.y;
  int z = chunk >> 2, c0 = (chunk & 3) * 32;
  const float* src = (z == 0) ? tf : (z == 1) ? ts : tl;
  int t = threadIdx.x;
  int p = t & 31, cl = t >> 5;
  __shared__ float sc_lds[S * P];   // [s][p]
  __shared__ int mi_lds[P];
  #pragma unroll
  for (int j = 0; j < 8; ++j) {
    int e = t + 256 * j;
    int s2 = e >> 5, pp = e & 31;
    sc_lds[s2 * P + pp] = score[((size_t)n * P + pp) * S + s2];
  }
  if (t < P) mi_lds[t] = mi[n * P + t];
  __syncthreads();
  int mymi = mi_lds[p];
  const float* base = src + (size_t)n * S * C * P + (size_t)(c0 + cl) * P + p;
  float acc[4] = {0.f, 0.f, 0.f, 0.f};
  float sel[4] = {0.f, 0.f, 0.f, 0.f};
  #pragma unroll 8
  for (int s = 0; s < S; ++s) {
    float scv = sc_lds[s * P + p];
    #pragma unroll
    for (int j = 0; j < 4; ++j) {
      float v = base[(size_t)s * C * P + j * 8 * P];
      acc[j] += v * scv;
      sel[j] = (s == mymi) ? v : sel[j];
    }
  }
  float* yp = y + ((size_t)p * N + n) * C3 + z * C + c0 + cl;
  #pragma unroll
  for (int j = 0; j < 4; ++j) yp[j * 8] = acc[j];
  if (z == 0) {
    float* sp = out_spf + ((size_t)p * N + n) * C + c0 + cl;
    #pragma unroll
    for (int j = 0; j < 4; ++j) sp[j * 8] = sel[j];
  }
}

// ============ K4: wpv = (wd . y)/Z, BN over n, write wpv + pf[p][c][n] ============
// grid (P, 8): block = 16 c x all 64 n.  thread: n = t&63, cg = t>>6 (4 c each)
__global__ __launch_bounds__(256) void k4_wpv(
    const float* __restrict__ y, const float* __restrict__ z,
    const float* __restrict__ wd, const float* __restrict__ g,
    const float* __restrict__ b, float* __restrict__ out_wpv,
    float* __restrict__ pf)
{
  int p   = blockIdx.x;
  int cch = blockIdx.y;             // 0..7
  int t = threadIdx.x;
  int n = t & 63, cg = t >> 6;
  int cbase = cch * 16 + cg * 4;
  __shared__ float ych[96][66];     // i-major, stride 66 -> 2-way (free)
  float acc[4] = {0.f, 0.f, 0.f, 0.f};
  const float* yp  = y  + (size_t)p * N * C3;
  const float* wdp = wd + (size_t)p * C * C3;
  for (int ch = 0; ch < 4; ++ch) {
    __syncthreads();
    #pragma unroll
    for (int j = 0; j < 24; ++j) {
      int e = t + 256 * j;
      int i = e % 96, nn = e / 96;
      ych[i][nn] = yp[nn * C3 + ch * 96 + i];
    }
    __syncthreads();
    #pragma unroll
    for (int sub = 0; sub < 4; ++sub) {
      float yr[24];
      #pragma unroll
      for (int kk = 0; kk < 24; ++kk) yr[kk] = ych[sub * 24 + kk][n];
      int ibase = ch * 96 + sub * 24;
      #pragma unroll
      for (int cl = 0; cl < 4; ++cl) {
        const float4* w4 = (const float4*)(wdp + (size_t)(cbase + cl) * C3 + ibase);
        float a = 0.f;
        #pragma unroll
        for (int q = 0; q < 6; ++q) {
          float4 wv = w4[q];
          a += yr[q*4+0] * wv.x + yr[q*4+1] * wv.y
             + yr[q*4+2] * wv.z + yr[q*4+3] * wv.w;
        }
        acc[cl] += a;
      }
    }
  }
  float zinv = 1.f / z[p * N + n];
  #pragma unroll
  for (int cl = 0; cl < 4; ++cl) acc[cl] *= zinv;
  // BN over n (wave lanes are exactly n=0..63 for fixed cg)
  #pragma unroll
  for (int cl = 0; cl < 4; ++cl) {
    float v = acc[cl];
    float s = v, q = v * v;
    #pragma unroll
    for (int m = 1; m < 64; m <<= 1) {
      s += __shfl_xor(s, m, 64);
      q += __shfl_xor(q, m, 64);
    }
    float mu  = s * (1.f / 64.f);
    float var = q * (1.f / 64.f) - mu * mu;
    int c = cbase + cl;
    float sc = g[p * C + c] * rsqrtf(var + EPSV);
    float sh = b[p * C + c] - mu * sc;
    pf[((size_t)p * C + c) * N + n] = v * sc + sh;   // coalesced over n
  }
  float4 wout = make_float4(acc[0], acc[1], acc[2], acc[3]);
  *(float4*)(out_wpv + ((size_t)p * N + n) * C + cbase) = wout;
}

// ============ K5: part_classification[p][n][k] = sum_c pf[p][c][n]*fc[c][k] ============
// grid (4 kt, P, 4 n-chunks), block 256: thread = one k, 16 n
__global__ __launch_bounds__(256) void k5_fc(
    const float* __restrict__ pf, const float* __restrict__ fc,
    float* __restrict__ out0)
{
  int kt = blockIdx.x;   // 0..3
  int p  = blockIdx.y;
  int n0 = blockIdx.z * 16;
  int t = threadIdx.x;
  int k = kt * 256 + t;
  bool ok = k < KCLS;
  int kk = ok ? k : (KCLS - 1);
  float acc[16];
  #pragma unroll
  for (int j = 0; j < 16; ++j) acc[j] = 0.f;
  for (int c = 0; c < C; ++c) {
    float fv = fc[c * KCLS + kk];
    const float4* row4 = (const float4*)(pf + ((size_t)p * C + c) * N + n0);
    #pragma unroll
    for (int j4 = 0; j4 < 4; ++j4) {
      float4 r = row4[j4];   // wave-uniform -> scalar loads
      acc[j4*4+0] += r.x * fv; acc[j4*4+1] += r.y * fv;
      acc[j4*4+2] += r.z * fv; acc[j4*4+3] += r.w * fv;
    }
  }
  if (ok) {
    #pragma unroll 4
    for (int j = 0; j < 16; ++j)
      out0[(size_t)(p * N + n0 + j) * KCLS + k] = acc[j];
  }
}

extern "C" void kernel_launch(void* const* d_in, const int* in_sizes, int n_in,
                              void* d_out, int out_size, void* d_ws, size_t ws_size,
                              hipStream_t stream)
{
  const float* tf = (const float*)d_in[0];
  const float* ts = (const float*)d_in[1];
  const float* tl = (const float*)d_in[2];
  const float* w1 = (const float*)d_in[3];
  const float* g1 = (const float*)d_in[4];
  const float* b1 = (const float*)d_in[5];
  const float* w2 = (const float*)d_in[6];
  const float* wd = (const float*)d_in[7];
  const float* g  = (const float*)d_in[8];
  const float* b  = (const float*)d_in[9];
  const float* fc = (const float*)d_in[10];

  float* ws   = (float*)d_ws;
  float* xT   = ws + WS_XT;
  float* h    = ws + WS_H;
  float* w1T  = ws + WS_W1T;
  float* bnp  = ws + WS_BNP;
  float* bnss = ws + WS_BNSS;
  float* y    = ws + WS_Y;
  float* z    = ws + WS_Z;
  float* pf   = ws + WS_PF;
  float* sc   = ws + WS_SC;
  int*   mi   = (int*)(ws + WS_MI);

  float* out0 = (float*)d_out;         // part_classification (P,N,K)
  float* out1 = out0 + P * N * KCLS;   // weighted_part_vector (P,N,C)
  float* out2 = out1 + P * N * C;      // selected_part_feature (P,N,C)

  k0_transpose<<<dim3(32, 64, 3), 256, 0, stream>>>(tf, ts, tl, xT);
  k0b_w1t<<<32, 256, 0, stream>>>(w1, w1T);
  k1_h<<<dim3(16, 32), 256, 0, stream>>>(xT, w1T, h, bnp);
  k2_bnstat<<<1, 768, 0, stream>>>(bnp, g1, b1, bnss);
  k3a_score<<<dim3(64, 8), 256, 0, stream>>>(h, bnss, w2, sc, z, mi);
  k3b_y<<<dim3(64, 12), 256, 0, stream>>>(tf, ts, tl, sc, mi, y, out2);
  k4_wpv<<<dim3(32, 8), 256, 0, stream>>>(y, z, wd, g, b, out1, pf);
  k5_fc<<<dim3(4, 32, 4), 256, 0, stream>>>(pf, fc, out0);
}

// Round 6
// 230.449 us; speedup vs baseline: 1.6883x; 1.2456x over previous
//
#include <hip/hip_runtime.h>
#include <math.h>

#define N 64
#define S 64
#define C 128
#define P 32
#define KCLS 1000
#define HPG 24
#define C3 384
#define NS 4096   /* N*S */
#define EPSV 1e-5f
#define SPAD 12   /* padded s-stride in k01 LDS tile */

// ---- workspace layout (float offsets) ----
#define WS_H    0                              // [P][HPG][NS]      3145728
#define WS_W1Z  (WS_H + P*HPG*NS)              // [384][8][32][4]    393216
#define WS_BNP  (WS_W1Z + 384*8*32*4)          // [512][768][2]      786432
#define WS_BNSS (WS_BNP + 512*768*2)           // [P*HPG][2]           1536
#define WS_Y    (WS_BNSS + P*HPG*2)            // [P][N][C3]         786432
#define WS_Z    (WS_Y + P*N*C3)                // [P][N]               2048
#define WS_PF   (WS_Z + P*N)                   // [P][C][N]          262144
#define WS_SC   (WS_PF + P*C*N)                // score [N][P][S]    131072
#define WS_MI   (WS_SC + N*P*S)                // argmax [N][P]        2048

// ============ K0w: w1[p][o][i] -> w1z[i][og][p][4] (o = og*3+oo, padded) ============
// 384*8*32 = 98304 float4 elements -> 384 blocks x 256 threads
__global__ __launch_bounds__(256) void k0w_w1z(
    const float* __restrict__ w1, float* __restrict__ w1z)
{
  int e = blockIdx.x * 256 + threadIdx.x;   // [0, 98304)
  int p = e & 31, og = (e >> 5) & 7, i = e >> 8;
  float4 v;
  v.x = w1[(p * HPG + og * 3 + 0) * C3 + i];
  v.y = w1[(p * HPG + og * 3 + 1) * C3 + i];
  v.z = w1[(p * HPG + og * 3 + 2) * C3 + i];
  v.w = 0.f;
  ((float4*)w1z)[e] = v;
}

// ============ K01: h[p][o][ns] = sum_i w1[p][o][i]*x[n,s,i,p] from RAW input ====
// grid (N, 8 s-tiles), block 256: og = t>>5 (3 o's), p = t&31; acc[3][8 s]
__global__ __launch_bounds__(256) void k01_h(
    const float* __restrict__ tf, const float* __restrict__ ts,
    const float* __restrict__ tl, const float* __restrict__ w1z,
    float* __restrict__ h, float* __restrict__ bnpart)
{
  int n = blockIdx.x, st = blockIdx.y;
  int s0 = st * 8;
  int t = threadIdx.x;
  int p = t & 31, og = t >> 5;
  __shared__ float xl[32 * 32 * SPAD];   // [c_loc][p][s(pad 12)] = 48 KB
  float accum[3][8];
  #pragma unroll
  for (int oo = 0; oo < 3; ++oo)
    #pragma unroll
    for (int s = 0; s < 8; ++s) accum[oo][s] = 0.f;

  const float4* w1z4 = (const float4*)w1z;
  for (int ch = 0; ch < 12; ++ch) {
    int z = ch >> 2, c0 = (ch & 3) * 32;
    const float* src = (z == 0) ? tf : (z == 1) ? ts : tl;
    const float* base = src + ((size_t)(n * S + s0)) * C * P + c0 * P;
    if (ch) __syncthreads();
    // stage 32 i x 8 s x 32 p (8 float4 loads per thread, coalesced)
    #pragma unroll
    for (int j = 0; j < 8; ++j) {
      int e = t + 256 * j;            // [0,2048) float4 index
      int s_loc = e >> 8;             // 256 float4 per s
      int idx = e & 255;
      int c_loc = idx >> 3, p0 = (idx & 7) * 4;
      float4 v = *(const float4*)&base[(size_t)s_loc * C * P + c_loc * P + p0];
      float* d = &xl[(c_loc * 32 + p0) * SPAD + s_loc];
      d[0] = v.x; d[SPAD] = v.y; d[2 * SPAD] = v.z; d[3 * SPAD] = v.w;
    }
    __syncthreads();
    #pragma unroll 4
    for (int cl = 0; cl < 32; ++cl) {
      float4 w4 = w1z4[((ch * 32 + cl) * 8 + og) * 32 + p];
      const float* xr = &xl[(cl * 32 + p) * SPAD];
      float4 lo = *(const float4*)&xr[0];
      float4 hi = *(const float4*)&xr[4];
      float xs[8] = {lo.x, lo.y, lo.z, lo.w, hi.x, hi.y, hi.z, hi.w};
      #pragma unroll
      for (int s = 0; s < 8; ++s) {
        accum[0][s] += w4.x * xs[s];
        accum[1][s] += w4.y * xs[s];
        accum[2][s] += w4.z * xs[s];
      }
    }
  }
  // write h + BN partials
  int nst = n * 8 + st;
  #pragma unroll
  for (int oo = 0; oo < 3; ++oo) {
    int o = og * 3 + oo;
    float* hp = h + (size_t)(p * HPG + o) * NS + n * S + s0;
    float4 lo = make_float4(accum[oo][0], accum[oo][1], accum[oo][2], accum[oo][3]);
    float4 hi = make_float4(accum[oo][4], accum[oo][5], accum[oo][6], accum[oo][7]);
    *(float4*)&hp[0] = lo;
    *(float4*)&hp[4] = hi;
    float sm = 0.f, sq = 0.f;
    #pragma unroll
    for (int s = 0; s < 8; ++s) { sm += accum[oo][s]; sq += accum[oo][s] * accum[oo][s]; }
    bnpart[(size_t)nst * 1536 + (p * HPG + o) * 2 + 0] = sm;
    bnpart[(size_t)nst * 1536 + (p * HPG + o) * 2 + 1] = sq;
  }
}

// ============ K2: finalize BN1 scale/shift (reduce 512 block partials) ============
__global__ void k2_bnstat(const float* __restrict__ bnpart,
    const float* __restrict__ g, const float* __restrict__ b,
    float* __restrict__ bnss)
{
  int t = threadIdx.x;  // 768 threads = P*HPG
  if (t >= P * HPG) return;
  float sum = 0.f, sq = 0.f;
  for (int j = 0; j < 512; ++j) {
    sum += bnpart[(size_t)j * 1536 + t * 2];
    sq  += bnpart[(size_t)j * 1536 + t * 2 + 1];
  }
  float mu  = sum / (float)NS;
  float var = sq / (float)NS - mu * mu;
  float sc = g[t] * rsqrtf(var + EPSV);
  bnss[t * 2]     = sc;
  bnss[t * 2 + 1] = b[t] - mu * sc;
}

// ============ K3a: score[n][p][s], Z, argmax index ============
// grid (N, 8 p-chunks), block 256 = 4 waves; wave -> one p; lane = s
__global__ __launch_bounds__(256) void k3a_score(
    const float* __restrict__ h, const float* __restrict__ bnss,
    const float* __restrict__ w2,
    float* __restrict__ score, float* __restrict__ z,
    int* __restrict__ mi_out)
{
  int n = blockIdx.x;
  int p = blockIdx.y * 4 + (threadIdx.x >> 6);
  int l = threadIdx.x & 63;   // = s
  float ssum = 0.f;
  const float* hp = h + (size_t)p * HPG * NS + n * S;
  #pragma unroll
  for (int o = 0; o < HPG; ++o) {
    float hv = hp[(size_t)o * NS + l];
    float sc = bnss[(p * HPG + o) * 2];
    float sh = bnss[(p * HPG + o) * 2 + 1];
    float v = hv * sc + sh;
    v = (v >= 0.f) ? v : 0.01f * v;
    ssum += w2[p * HPG + o] * v;
  }
  float scr = 1.f / (1.f + expf(-ssum));
  float zs = scr;
  #pragma unroll
  for (int m = 1; m < 64; m <<= 1) zs += __shfl_xor(zs, m, 64);
  float mv = scr; int mi = l;
  #pragma unroll
  for (int m = 1; m < 64; m <<= 1) {
    float ov = __shfl_xor(mv, m, 64);
    int   oi = __shfl_xor(mi, m, 64);
    if (ov > mv || (ov == mv && oi < mi)) { mv = ov; mi = oi; }
  }
  if (l == 0) { z[p * N + n] = zs; mi_out[n * P + p] = mi; }
  score[((size_t)n * P + p) * S + l] = scr;
}

// ============ K3b: y[p][n][i] = sum_s x[n,s,i,p]*score[n,p,s], from RAW input ====
// also grabs selected = x[n, mi[p], c, p] (z==0 chunks) while streaming s.
__global__ __launch_bounds__(256) void k3b_y(
    const float* __restrict__ tf, const float* __restrict__ ts,
    const float* __restrict__ tl, const float* __restrict__ score,
    const int* __restrict__ mi, float* __restrict__ y,
    float* __restrict__ out_spf)
{
  int n = blockIdx.x, chunk = blockIdx.y;
  int z = chunk >> 2, c0 = (chunk & 3) * 32;
  const float* src = (z == 0) ? tf : (z == 1) ? ts : tl;
  int t = threadIdx.x;
  int p = t & 31, cl = t >> 5;
  __shared__ float sc_lds[S * P];   // [s][p]
  __shared__ int mi_lds[P];
  #pragma unroll
  for (int j = 0; j < 8; ++j) {
    int e = t + 256 * j;
    int s2 = e >> 5, pp = e & 31;
    sc_lds[s2 * P + pp] = score[((size_t)n * P + pp) * S + s2];
  }
  if (t < P) mi_lds[t] = mi[n * P + t];
  __syncthreads();
  int mymi = mi_lds[p];
  const float* base = src + (size_t)n * S * C * P + (size_t)(c0 + cl) * P + p;
  float acc[4] = {0.f, 0.f, 0.f, 0.f};
  float sel[4] = {0.f, 0.f, 0.f, 0.f};
  #pragma unroll 8
  for (int s = 0; s < S; ++s) {
    float scv = sc_lds[s * P + p];
    #pragma unroll
    for (int j = 0; j < 4; ++j) {
      float v = base[(size_t)s * C * P + j * 8 * P];
      acc[j] += v * scv;
      sel[j] = (s == mymi) ? v : sel[j];
    }
  }
  float* yp = y + ((size_t)p * N + n) * C3 + z * C + c0 + cl;
  #pragma unroll
  for (int j = 0; j < 4; ++j) yp[j * 8] = acc[j];
  if (z == 0) {
    float* sp = out_spf + ((size_t)p * N + n) * C + c0 + cl;
    #pragma unroll
    for (int j = 0; j < 4; ++j) sp[j * 8] = sel[j];
  }
}

// ============ K4: wpv = (wd . y)/Z, BN over n, write wpv + pf[p][c][n] ============
__global__ __launch_bounds__(256) void k4_wpv(
    const float* __restrict__ y, const float* __restrict__ z,
    const float* __restrict__ wd, const float* __restrict__ g,
    const float* __restrict__ b, float* __restrict__ out_wpv,
    float* __restrict__ pf)
{
  int p   = blockIdx.x;
  int cch = blockIdx.y;             // 0..7
  int t = threadIdx.x;
  int n = t & 63, cg = t >> 6;
  int cbase = cch * 16 + cg * 4;
  __shared__ float ych[96][66];     // i-major, stride 66 -> 2-way (free)
  float acc[4] = {0.f, 0.f, 0.f, 0.f};
  const float* yp  = y  + (size_t)p * N * C3;
  const float* wdp = wd + (size_t)p * C * C3;
  for (int ch = 0; ch < 4; ++ch) {
    __syncthreads();
    #pragma unroll
    for (int j = 0; j < 24; ++j) {
      int e = t + 256 * j;
      int i = e % 96, nn = e / 96;
      ych[i][nn] = yp[nn * C3 + ch * 96 + i];
    }
    __syncthreads();
    #pragma unroll
    for (int sub = 0; sub < 4; ++sub) {
      float yr[24];
      #pragma unroll
      for (int kk = 0; kk < 24; ++kk) yr[kk] = ych[sub * 24 + kk][n];
      int ibase = ch * 96 + sub * 24;
      #pragma unroll
      for (int cl = 0; cl < 4; ++cl) {
        const float4* w4 = (const float4*)(wdp + (size_t)(cbase + cl) * C3 + ibase);
        float a = 0.f;
        #pragma unroll
        for (int q = 0; q < 6; ++q) {
          float4 wv = w4[q];
          a += yr[q*4+0] * wv.x + yr[q*4+1] * wv.y
             + yr[q*4+2] * wv.z + yr[q*4+3] * wv.w;
        }
        acc[cl] += a;
      }
    }
  }
  float zinv = 1.f / z[p * N + n];
  #pragma unroll
  for (int cl = 0; cl < 4; ++cl) acc[cl] *= zinv;
  #pragma unroll
  for (int cl = 0; cl < 4; ++cl) {
    float v = acc[cl];
    float s = v, q = v * v;
    #pragma unroll
    for (int m = 1; m < 64; m <<= 1) {
      s += __shfl_xor(s, m, 64);
      q += __shfl_xor(q, m, 64);
    }
    float mu  = s * (1.f / 64.f);
    float var = q * (1.f / 64.f) - mu * mu;
    int c = cbase + cl;
    float sc = g[p * C + c] * rsqrtf(var + EPSV);
    float sh = b[p * C + c] - mu * sc;
    pf[((size_t)p * C + c) * N + n] = v * sc + sh;   // coalesced over n
  }
  float4 wout = make_float4(acc[0], acc[1], acc[2], acc[3]);
  *(float4*)(out_wpv + ((size_t)p * N + n) * C + cbase) = wout;
}

// ============ K5: part_classification[p][n][k] = sum_c pf[p][c][n]*fc[c][k] ============
__global__ __launch_bounds__(256) void k5_fc(
    const float* __restrict__ pf, const float* __restrict__ fc,
    float* __restrict__ out0)
{
  int kt = blockIdx.x;   // 0..3
  int p  = blockIdx.y;
  int n0 = blockIdx.z * 16;
  int t = threadIdx.x;
  int k = kt * 256 + t;
  bool ok = k < KCLS;
  int kk = ok ? k : (KCLS - 1);
  float acc[16];
  #pragma unroll
  for (int j = 0; j < 16; ++j) acc[j] = 0.f;
  for (int c = 0; c < C; ++c) {
    float fv = fc[c * KCLS + kk];
    const float4* row4 = (const float4*)(pf + ((size_t)p * C + c) * N + n0);
    #pragma unroll
    for (int j4 = 0; j4 < 4; ++j4) {
      float4 r = row4[j4];   // wave-uniform -> scalar loads
      acc[j4*4+0] += r.x * fv; acc[j4*4+1] += r.y * fv;
      acc[j4*4+2] += r.z * fv; acc[j4*4+3] += r.w * fv;
    }
  }
  if (ok) {
    #pragma unroll 4
    for (int j = 0; j < 16; ++j)
      out0[(size_t)(p * N + n0 + j) * KCLS + k] = acc[j];
  }
}

extern "C" void kernel_launch(void* const* d_in, const int* in_sizes, int n_in,
                              void* d_out, int out_size, void* d_ws, size_t ws_size,
                              hipStream_t stream)
{
  const float* tf = (const float*)d_in[0];
  const float* ts = (const float*)d_in[1];
  const float* tl = (const float*)d_in[2];
  const float* w1 = (const float*)d_in[3];
  const float* g1 = (const float*)d_in[4];
  const float* b1 = (const float*)d_in[5];
  const float* w2 = (const float*)d_in[6];
  const float* wd = (const float*)d_in[7];
  const float* g  = (const float*)d_in[8];
  const float* b  = (const float*)d_in[9];
  const float* fc = (const float*)d_in[10];

  float* ws   = (float*)d_ws;
  float* h    = ws + WS_H;
  float* w1z  = ws + WS_W1Z;
  float* bnp  = ws + WS_BNP;
  float* bnss = ws + WS_BNSS;
  float* y    = ws + WS_Y;
  float* z    = ws + WS_Z;
  float* pf   = ws + WS_PF;
  float* sc   = ws + WS_SC;
  int*   mi   = (int*)(ws + WS_MI);

  float* out0 = (float*)d_out;         // part_classification (P,N,K)
  float* out1 = out0 + P * N * KCLS;   // weighted_part_vector (P,N,C)
  float* out2 = out1 + P * N * C;      // selected_part_feature (P,N,C)

  k0w_w1z<<<384, 256, 0, stream>>>(w1, w1z);
  k01_h<<<dim3(64, 8), 256, 0, stream>>>(tf, ts, tl, w1z, h, bnp);
  k2_bnstat<<<1, 768, 0, stream>>>(bnp, g1, b1, bnss);
  k3a_score<<<dim3(64, 8), 256, 0, stream>>>(h, bnss, w2, sc, z, mi);
  k3b_y<<<dim3(64, 12), 256, 0, stream>>>(tf, ts, tl, sc, mi, y, out2);
  k4_wpv<<<dim3(32, 8), 256, 0, stream>>>(y, z, wd, g, b, out1, pf);
  k5_fc<<<dim3(4, 32, 4), 256, 0, stream>>>(pf, fc, out0);
}

// Round 8
// 209.048 us; speedup vs baseline: 1.8611x; 1.1024x over previous
//
#include <hip/hip_runtime.h>
#include <math.h>

#define N 64
#define S 64
#define C 128
#define P 32
#define KCLS 1000
#define HPG 24
#define C3 384
#define NS 4096   /* N*S */
#define EPSV 1e-5f

// ---- workspace layout (float offsets) ----
#define WS_H    0                              // [P][HPG][NS]      3145728
#define WS_W1Z  (WS_H + P*HPG*NS)              // [384][2][3][32][4] 294912 (393216 reserved)
#define WS_BNP  (WS_W1Z + 384*8*32*4)          // bnpartT [1536][512] 786432
#define WS_BNSS (WS_BNP + 512*768*2)           // [P*HPG][2]           1536
#define WS_Y    (WS_BNSS + P*HPG*2)            // [P][N][C3]         786432
#define WS_Z    (WS_Y + P*N*C3)                // [P][N]               2048
#define WS_PF   (WS_Z + P*N)                   // [P][C][N]          262144
#define WS_SC   (WS_PF + P*C*N)                // score [N][P][S]    131072
#define WS_MI   (WS_SC + N*P*S)                // argmax [N][P]        2048

// ============ K0w: w1[p][o][i] -> w1z[i][og2][j4][p] float4 ============
// o = og2*12 + j4*4 + comp;  73728 float4 -> 288 blocks x 256
__global__ __launch_bounds__(256) void k0w_w1z(
    const float* __restrict__ w1, float* __restrict__ w1z)
{
  int e = blockIdx.x * 256 + threadIdx.x;   // [0, 73728)
  int p = e & 31;
  int r = e >> 5;
  int j4 = r % 3;
  int r2 = r / 3;
  int og2 = r2 & 1;
  int i = r2 >> 1;
  float4 v;
  v.x = w1[(p * HPG + og2 * 12 + j4 * 4 + 0) * C3 + i];
  v.y = w1[(p * HPG + og2 * 12 + j4 * 4 + 1) * C3 + i];
  v.z = w1[(p * HPG + og2 * 12 + j4 * 4 + 2) * C3 + i];
  v.w = w1[(p * HPG + og2 * 12 + j4 * 4 + 3) * C3 + i];
  ((float4*)w1z)[e] = v;
}

// ============ K01: h[p][o][ns] = sum_i w1[p][o][i]*x[n,s,i,p] from RAW input ====
// grid (N, 8 s-tiles), block 256: p = t&31, og2 = (t>>5)&1, s2 = t>>6
// thread: 12 o's x 2 s.  LDS identity tile [s8][c32][p32] = 32 KB, conflict-free.
__global__ __launch_bounds__(256) void k01_h(
    const float* __restrict__ tf, const float* __restrict__ ts,
    const float* __restrict__ tl, const float* __restrict__ w1z,
    float* __restrict__ h, float* __restrict__ bnpT)
{
  int n = blockIdx.x, st = blockIdx.y;
  int s0 = st * 8;
  int t = threadIdx.x;
  int p = t & 31;
  int og2 = (t >> 5) & 1;
  int s2 = t >> 6;            // 0..3
  __shared__ float xl[8 * 1024];   // 32 KB; reused as bnred at the end
  float acc[12][2];
  #pragma unroll
  for (int oo = 0; oo < 12; ++oo) { acc[oo][0] = 0.f; acc[oo][1] = 0.f; }

  const float4* w4p = (const float4*)w1z;
  for (int ch = 0; ch < 12; ++ch) {
    int z = ch >> 2, c0 = (ch & 3) * 32;
    const float* src = (z == 0) ? tf : (z == 1) ? ts : tl;
    const float* base = src + ((size_t)(n * S + s0)) * C * P + c0 * P;
    if (ch) __syncthreads();
    // identity staging: contiguous copy, b128 writes, no conflicts
    #pragma unroll
    for (int j = 0; j < 8; ++j) {
      int e = t + 256 * j;          // float4 index [0,2048)
      int s_loc = e >> 8;
      int idx = e & 255;
      float4 v = *(const float4*)&base[(size_t)s_loc * C * P + idx * 4];
      *(float4*)&xl[s_loc * 1024 + idx * 4] = v;
    }
    __syncthreads();
    const float* x0p = &xl[(s2 * 2 + 0) * 1024 + p];
    const float* x1p = &xl[(s2 * 2 + 1) * 1024 + p];
    #pragma unroll 2
    for (int cl = 0; cl < 32; ++cl) {
      int i = ch * 32 + cl;
      int wbase = ((i * 2 + og2) * 3) * 32 + p;
      float4 w0 = w4p[wbase];
      float4 w1_ = w4p[wbase + 32];
      float4 w2_ = w4p[wbase + 64];
      float x0 = x0p[cl * 32];      // bank = p, conflict-free + og2 broadcast
      float x1 = x1p[cl * 32];
      float wv[12] = {w0.x, w0.y, w0.z, w0.w, w1_.x, w1_.y, w1_.z, w1_.w,
                      w2_.x, w2_.y, w2_.z, w2_.w};
      #pragma unroll
      for (int oo = 0; oo < 12; ++oo) {
        acc[oo][0] += wv[oo] * x0;
        acc[oo][1] += wv[oo] * x1;
      }
    }
  }
  // h writes (L2 merges partial lines) + per-thread BN partials into LDS
  __syncthreads();                  // all xl reads done; reuse as bnred
  float* bnred = xl;                // [(og2*12+oo)][s2][q][p] = 6144 floats
  int sg = n * S + s0 + s2 * 2;
  #pragma unroll
  for (int oo = 0; oo < 12; ++oo) {
    int o = og2 * 12 + oo;
    float a0 = acc[oo][0], a1 = acc[oo][1];
    *(float2*)&h[(size_t)(p * HPG + o) * NS + sg] = make_float2(a0, a1);
    bnred[(((o * 4 + s2) * 2) + 0) * 32 + p] = a0 + a1;
    bnred[(((o * 4 + s2) * 2) + 1) * 32 + p] = a0 * a0 + a1 * a1;
  }
  __syncthreads();
  // reduce s2 and write bnpartT[(p*24+o)*2+q][nst]; 256 threads cover 768 rows
  int nst = n * 8 + st;
  #pragma unroll
  for (int rep = 0; rep < 3; ++rep) {
    int p3 = t & 31, o3 = (t >> 5) + rep * 8;   // o3 0..23
    float sm = 0.f, sq = 0.f;
    #pragma unroll
    for (int j = 0; j < 4; ++j) {
      sm += bnred[((o3 * 4 + j) * 2 + 0) * 32 + p3];
      sq += bnred[((o3 * 4 + j) * 2 + 1) * 32 + p3];
    }
    bnpT[(size_t)((p3 * HPG + o3) * 2 + 0) * 512 + nst] = sm;
    bnpT[(size_t)((p3 * HPG + o3) * 2 + 1) * 512 + nst] = sq;
  }
}

// ============ K2: finalize BN1 scale/shift; 96 blocks x 16 rows ============
__global__ __launch_bounds__(256) void k2_bnstat(const float* __restrict__ bnpT,
    const float* __restrict__ g, const float* __restrict__ b,
    float* __restrict__ bnss)
{
  int blk = blockIdx.x;            // 0..95
  int t = threadIdx.x;
  int rl = t >> 4, lane = t & 15;
  int row = blk * 16 + rl;         // 0..1535
  const float* rp = bnpT + (size_t)row * 512;
  float sm = 0.f;
  #pragma unroll 8
  for (int j = 0; j < 32; ++j) sm += rp[lane + 16 * j];
  __shared__ float red[16][17];
  red[rl][lane] = sm;
  __syncthreads();
  if (t < 16) {
    float s = 0.f;
    #pragma unroll
    for (int j = 0; j < 16; ++j) s += red[t][j];
    red[t][16] = s;
  }
  __syncthreads();
  if (t < 8) {
    int po = blk * 8 + t;          // (p*24+o)
    float sum = red[t * 2][16];
    float sq  = red[t * 2 + 1][16];
    float mu  = sum / (float)NS;
    float var = sq / (float)NS - mu * mu;
    float sc = g[po] * rsqrtf(var + EPSV);
    bnss[po * 2]     = sc;
    bnss[po * 2 + 1] = b[po] - mu * sc;
  }
}

// ============ K3a: score[n][p][s], Z, argmax index ============
__global__ __launch_bounds__(256) void k3a_score(
    const float* __restrict__ h, const float* __restrict__ bnss,
    const float* __restrict__ w2,
    float* __restrict__ score, float* __restrict__ z,
    int* __restrict__ mi_out)
{
  int n = blockIdx.x;
  int p = blockIdx.y * 4 + (threadIdx.x >> 6);
  int l = threadIdx.x & 63;   // = s
  float ssum = 0.f;
  const float* hp = h + (size_t)p * HPG * NS + n * S;
  #pragma unroll
  for (int o = 0; o < HPG; ++o) {
    float hv = hp[(size_t)o * NS + l];
    float sc = bnss[(p * HPG + o) * 2];
    float sh = bnss[(p * HPG + o) * 2 + 1];
    float v = hv * sc + sh;
    v = (v >= 0.f) ? v : 0.01f * v;
    ssum += w2[p * HPG + o] * v;
  }
  float scr = 1.f / (1.f + expf(-ssum));
  float zs = scr;
  #pragma unroll
  for (int m = 1; m < 64; m <<= 1) zs += __shfl_xor(zs, m, 64);
  float mv = scr; int mi = l;
  #pragma unroll
  for (int m = 1; m < 64; m <<= 1) {
    float ov = __shfl_xor(mv, m, 64);
    int   oi = __shfl_xor(mi, m, 64);
    if (ov > mv || (ov == mv && oi < mi)) { mv = ov; mi = oi; }
  }
  if (l == 0) { z[p * N + n] = zs; mi_out[n * P + p] = mi; }
  score[((size_t)n * P + p) * S + l] = scr;
}

// ============ K3b: y[p][n][i] = sum_s x[n,s,i,p]*score[n,p,s], raw input ====
__global__ __launch_bounds__(256) void k3b_y(
    const float* __restrict__ tf, const float* __restrict__ ts,
    const float* __restrict__ tl, const float* __restrict__ score,
    const int* __restrict__ mi, float* __restrict__ y,
    float* __restrict__ out_spf)
{
  int n = blockIdx.x, chunk = blockIdx.y;
  int z = chunk >> 2, c0 = (chunk & 3) * 32;
  const float* src = (z == 0) ? tf : (z == 1) ? ts : tl;
  int t = threadIdx.x;
  int p = t & 31, cl = t >> 5;
  __shared__ float sc_lds[S * P];   // [s][p]
  __shared__ int mi_lds[P];
  #pragma unroll
  for (int j = 0; j < 8; ++j) {
    int e = t + 256 * j;
    int s2 = e >> 5, pp = e & 31;
    sc_lds[s2 * P + pp] = score[((size_t)n * P + pp) * S + s2];
  }
  if (t < P) mi_lds[t] = mi[n * P + t];
  __syncthreads();
  int mymi = mi_lds[p];
  const float* base = src + (size_t)n * S * C * P + (size_t)(c0 + cl) * P + p;
  float acc[4] = {0.f, 0.f, 0.f, 0.f};
  float sel[4] = {0.f, 0.f, 0.f, 0.f};
  #pragma unroll 8
  for (int s = 0; s < S; ++s) {
    float scv = sc_lds[s * P + p];
    #pragma unroll
    for (int j = 0; j < 4; ++j) {
      float v = base[(size_t)s * C * P + j * 8 * P];
      acc[j] += v * scv;
      sel[j] = (s == mymi) ? v : sel[j];
    }
  }
  float* yp = y + ((size_t)p * N + n) * C3 + z * C + c0 + cl;
  #pragma unroll
  for (int j = 0; j < 4; ++j) yp[j * 8] = acc[j];
  if (z == 0) {
    float* sp = out_spf + ((size_t)p * N + n) * C + c0 + cl;
    #pragma unroll
    for (int j = 0; j < 4; ++j) sp[j * 8] = sel[j];
  }
}

// ============ K4: wpv = (wd . y)/Z, BN over n, write wpv + pf[p][c][n] ============
__global__ __launch_bounds__(256) void k4_wpv(
    const float* __restrict__ y, const float* __restrict__ z,
    const float* __restrict__ wd, const float* __restrict__ g,
    const float* __restrict__ b, float* __restrict__ out_wpv,
    float* __restrict__ pf)
{
  int p   = blockIdx.x;
  int cch = blockIdx.y;             // 0..7
  int t = threadIdx.x;
  int n = t & 63, cg = t >> 6;
  int cbase = cch * 16 + cg * 4;
  __shared__ float ych[96][66];     // i-major, stride 66 -> 2-way (free)
  float acc[4] = {0.f, 0.f, 0.f, 0.f};
  const float* yp  = y  + (size_t)p * N * C3;
  const float* wdp = wd + (size_t)p * C * C3;
  for (int ch = 0; ch < 4; ++ch) {
    __syncthreads();
    #pragma unroll
    for (int j = 0; j < 24; ++j) {
      int e = t + 256 * j;
      int i = e % 96, nn = e / 96;
      ych[i][nn] = yp[nn * C3 + ch * 96 + i];
    }
    __syncthreads();
    #pragma unroll
    for (int sub = 0; sub < 4; ++sub) {
      float yr[24];
      #pragma unroll
      for (int kk = 0; kk < 24; ++kk) yr[kk] = ych[sub * 24 + kk][n];
      int ibase = ch * 96 + sub * 24;
      #pragma unroll
      for (int cl = 0; cl < 4; ++cl) {
        const float4* w4 = (const float4*)(wdp + (size_t)(cbase + cl) * C3 + ibase);
        float a = 0.f;
        #pragma unroll
        for (int q = 0; q < 6; ++q) {
          float4 wv = w4[q];
          a += yr[q*4+0] * wv.x + yr[q*4+1] * wv.y
             + yr[q*4+2] * wv.z + yr[q*4+3] * wv.w;
        }
        acc[cl] += a;
      }
    }
  }
  float zinv = 1.f / z[p * N + n];
  #pragma unroll
  for (int cl = 0; cl < 4; ++cl) acc[cl] *= zinv;
  #pragma unroll
  for (int cl = 0; cl < 4; ++cl) {
    float v = acc[cl];
    float s = v, q = v * v;
    #pragma unroll
    for (int m = 1; m < 64; m <<= 1) {
      s += __shfl_xor(s, m, 64);
      q += __shfl_xor(q, m, 64);
    }
    float mu  = s * (1.f / 64.f);
    float var = q * (1.f / 64.f) - mu * mu;
    int c = cbase + cl;
    float sc = g[p * C + c] * rsqrtf(var + EPSV);
    float sh = b[p * C + c] - mu * sc;
    pf[((size_t)p * C + c) * N + n] = v * sc + sh;   // coalesced over n
  }
  float4 wout = make_float4(acc[0], acc[1], acc[2], acc[3]);
  *(float4*)(out_wpv + ((size_t)p * N + n) * C + cbase) = wout;
}

// ============ K5: part_classification[p][n][k] = sum_c pf[p][c][n]*fc[c][k] ============
__global__ __launch_bounds__(256) void k5_fc(
    const float* __restrict__ pf, const float* __restrict__ fc,
    float* __restrict__ out0)
{
  int kt = blockIdx.x;   // 0..3
  int p  = blockIdx.y;
  int n0 = blockIdx.z * 16;
  int t = threadIdx.x;
  int k = kt * 256 + t;
  bool ok = k < KCLS;
  int kk = ok ? k : (KCLS - 1);
  float acc[16];
  #pragma unroll
  for (int j = 0; j < 16; ++j) acc[j] = 0.f;
  for (int c = 0; c < C; ++c) {
    float fv = fc[c * KCLS + kk];
    const float4* row4 = (const float4*)(pf + ((size_t)p * C + c) * N + n0);
    #pragma unroll
    for (int j4 = 0; j4 < 4; ++j4) {
      float4 r = row4[j4];   // wave-uniform -> scalar loads
      acc[j4*4+0] += r.x * fv; acc[j4*4+1] += r.y * fv;
      acc[j4*4+2] += r.z * fv; acc[j4*4+3] += r.w * fv;
    }
  }
  if (ok) {
    #pragma unroll 4
    for (int j = 0; j < 16; ++j)
      out0[(size_t)(p * N + n0 + j) * KCLS + k] = acc[j];
  }
}

extern "C" void kernel_launch(void* const* d_in, const int* in_sizes, int n_in,
                              void* d_out, int out_size, void* d_ws, size_t ws_size,
                              hipStream_t stream)
{
  const float* tf = (const float*)d_in[0];
  const float* ts = (const float*)d_in[1];
  const float* tl = (const float*)d_in[2];
  const float* w1 = (const float*)d_in[3];
  const float* g1 = (const float*)d_in[4];
  const float* b1 = (const float*)d_in[5];
  const float* w2 = (const float*)d_in[6];
  const float* wd = (const float*)d_in[7];
  const float* g  = (const float*)d_in[8];
  const float* b  = (const float*)d_in[9];
  const float* fc = (const float*)d_in[10];

  float* ws   = (float*)d_ws;
  float* h    = ws + WS_H;
  float* w1z  = ws + WS_W1Z;
  float* bnpT = ws + WS_BNP;
  float* bnss = ws + WS_BNSS;
  float* y    = ws + WS_Y;
  float* z    = ws + WS_Z;
  float* pf   = ws + WS_PF;
  float* sc   = ws + WS_SC;
  int*   mi   = (int*)(ws + WS_MI);

  float* out0 = (float*)d_out;         // part_classification (P,N,K)
  float* out1 = out0 + P * N * KCLS;   // weighted_part_vector (P,N,C)
  float* out2 = out1 + P * N * C;      // selected_part_feature (P,N,C)

  k0w_w1z<<<288, 256, 0, stream>>>(w1, w1z);
  k01_h<<<dim3(64, 8), 256, 0, stream>>>(tf, ts, tl, w1z, h, bnpT);
  k2_bnstat<<<96, 256, 0, stream>>>(bnpT, g1, b1, bnss);
  k3a_score<<<dim3(64, 8), 256, 0, stream>>>(h, bnss, w2, sc, z, mi);
  k3b_y<<<dim3(64, 12), 256, 0, stream>>>(tf, ts, tl, sc, mi, y, out2);
  k4_wpv<<<dim3(32, 8), 256, 0, stream>>>(y, z, wd, g, b, out1, pf);
  k5_fc<<<dim3(4, 32, 4), 256, 0, stream>>>(pf, fc, out0);
}

// Round 9
// 168.643 us; speedup vs baseline: 2.3070x; 1.2396x over previous
//
#include <hip/hip_runtime.h>
#include <math.h>

#define N 64
#define S 64
#define C 128
#define P 32
#define KCLS 1000
#define HPG 24
#define C3 384
#define NS 4096   /* N*S */
#define EPSV 1e-5f

// ---- workspace layout (float offsets) ----
#define WS_H    0                              // [P][HPG][NS]      3145728
#define WS_W1Z  (WS_H + P*HPG*NS)              // [384][8][32][4]    393216
#define WS_BNP  (WS_W1Z + 384*8*32*4)          // bnpartT [1536][512] 786432
#define WS_BNSS (WS_BNP + 512*768*2)           // [P*HPG][2]           1536
#define WS_Y    (WS_BNSS + P*HPG*2)            // [P][N][C3]         786432
#define WS_Z    (WS_Y + P*N*C3)                // [P][N]               2048
#define WS_PF   (WS_Z + P*N)                   // [P][C][N]          262144
#define WS_SC   (WS_PF + P*C*N)                // score [N][P][S]    131072
#define WS_MI   (WS_SC + N*P*S)                // argmax [N][P]        2048

// ============ K0w: w1[p][o][i] -> w1z[i][og][p][4], o = og*3 + comp ============
// 384*8*32 = 98304 float4 -> 384 blocks x 256
__global__ __launch_bounds__(256) void k0w_w1z(
    const float* __restrict__ w1, float* __restrict__ w1z)
{
  int e = blockIdx.x * 256 + threadIdx.x;   // [0, 98304)
  int p = e & 31;
  int og = (e >> 5) & 7;
  int i = e >> 8;
  float4 v;
  v.x = w1[(p * HPG + og * 3 + 0) * C3 + i];
  v.y = w1[(p * HPG + og * 3 + 1) * C3 + i];
  v.z = w1[(p * HPG + og * 3 + 2) * C3 + i];
  v.w = 0.f;
  ((float4*)w1z)[e] = v;
}

// ============ K01: h[p][o][ns] = sum_i w1[p][o][i]*x[n,s,i,p] from RAW input ====
// grid (N, 8 s-tiles), block 256: p = t&31, og = t>>5 (3 o's x all 8 s).
// Per i: 1 float4 w-load + 8 LDS b32 (lane-broadcast halves) + 24 FMA.
__global__ __launch_bounds__(256) void k01_h(
    const float* __restrict__ tf, const float* __restrict__ ts,
    const float* __restrict__ tl, const float* __restrict__ w1z,
    float* __restrict__ h, float* __restrict__ bnpT)
{
  int n = blockIdx.x, st = blockIdx.y;
  int s0 = st * 8;
  int t = threadIdx.x;
  int p = t & 31;
  int og = t >> 5;            // 0..7
  __shared__ float xl[8 * 1024];   // [s8][c32][p32] = 32 KB, identity layout
  float acc[3][8];
  #pragma unroll
  for (int oo = 0; oo < 3; ++oo)
    #pragma unroll
    for (int s = 0; s < 8; ++s) acc[oo][s] = 0.f;

  const float4* w4p = (const float4*)w1z;
  const float* xp = &xl[p];
  for (int ch = 0; ch < 12; ++ch) {
    int z = ch >> 2, c0 = (ch & 3) * 32;
    const float* src = (z == 0) ? tf : (z == 1) ? ts : tl;
    const float* base = src + ((size_t)(n * S + s0)) * C * P + c0 * P;
    if (ch) __syncthreads();
    // identity staging: contiguous copy, b128 both sides, no conflicts
    #pragma unroll
    for (int j = 0; j < 8; ++j) {
      int e = t + 256 * j;          // float4 index [0,2048)
      int s_loc = e >> 8;
      int idx = e & 255;
      float4 v = *(const float4*)&base[(size_t)s_loc * C * P + idx * 4];
      *(float4*)&xl[s_loc * 1024 + idx * 4] = v;
    }
    __syncthreads();
    #pragma unroll 4
    for (int cl = 0; cl < 32; ++cl) {
      int i = ch * 32 + cl;
      float4 w = w4p[(i * 8 + og) * 32 + p];   // coalesced 1KB/wave, L2-resident
      float xs[8];
      #pragma unroll
      for (int s = 0; s < 8; ++s) xs[s] = xp[s * 1024 + cl * 32];  // bank=p, bcast
      #pragma unroll
      for (int s = 0; s < 8; ++s) {
        acc[0][s] += w.x * xs[s];
        acc[1][s] += w.y * xs[s];
        acc[2][s] += w.z * xs[s];
      }
    }
  }
  // h writes + BN partials (each thread owns complete 8-s sums)
  int nst = n * 8 + st;
  #pragma unroll
  for (int oo = 0; oo < 3; ++oo) {
    int o = og * 3 + oo;
    float* hp = h + (size_t)(p * HPG + o) * NS + n * S + s0;
    *(float4*)&hp[0] = make_float4(acc[oo][0], acc[oo][1], acc[oo][2], acc[oo][3]);
    *(float4*)&hp[4] = make_float4(acc[oo][4], acc[oo][5], acc[oo][6], acc[oo][7]);
    float sm = 0.f, sq = 0.f;
    #pragma unroll
    for (int s = 0; s < 8; ++s) { sm += acc[oo][s]; sq += acc[oo][s] * acc[oo][s]; }
    bnpT[(size_t)((p * HPG + o) * 2 + 0) * 512 + nst] = sm;
    bnpT[(size_t)((p * HPG + o) * 2 + 1) * 512 + nst] = sq;
  }
}

// ============ K2: finalize BN1 scale/shift; 96 blocks x 16 rows ============
__global__ __launch_bounds__(256) void k2_bnstat(const float* __restrict__ bnpT,
    const float* __restrict__ g, const float* __restrict__ b,
    float* __restrict__ bnss)
{
  int blk = blockIdx.x;            // 0..95
  int t = threadIdx.x;
  int rl = t >> 4, lane = t & 15;
  int row = blk * 16 + rl;         // 0..1535
  const float* rp = bnpT + (size_t)row * 512;
  float sm = 0.f;
  #pragma unroll 8
  for (int j = 0; j < 32; ++j) sm += rp[lane + 16 * j];
  __shared__ float red[16][17];
  red[rl][lane] = sm;
  __syncthreads();
  if (t < 16) {
    float s = 0.f;
    #pragma unroll
    for (int j = 0; j < 16; ++j) s += red[t][j];
    red[t][16] = s;
  }
  __syncthreads();
  if (t < 8) {
    int po = blk * 8 + t;          // (p*24+o)
    float sum = red[t * 2][16];
    float sq  = red[t * 2 + 1][16];
    float mu  = sum / (float)NS;
    float var = sq / (float)NS - mu * mu;
    float sc = g[po] * rsqrtf(var + EPSV);
    bnss[po * 2]     = sc;
    bnss[po * 2 + 1] = b[po] - mu * sc;
  }
}

// ============ K3a: score[n][p][s], Z, argmax index ============
__global__ __launch_bounds__(256) void k3a_score(
    const float* __restrict__ h, const float* __restrict__ bnss,
    const float* __restrict__ w2,
    float* __restrict__ score, float* __restrict__ z,
    int* __restrict__ mi_out)
{
  int n = blockIdx.x;
  int p = blockIdx.y * 4 + (threadIdx.x >> 6);
  int l = threadIdx.x & 63;   // = s
  float ssum = 0.f;
  const float* hp = h + (size_t)p * HPG * NS + n * S;
  #pragma unroll
  for (int o = 0; o < HPG; ++o) {
    float hv = hp[(size_t)o * NS + l];
    float sc = bnss[(p * HPG + o) * 2];
    float sh = bnss[(p * HPG + o) * 2 + 1];
    float v = hv * sc + sh;
    v = (v >= 0.f) ? v : 0.01f * v;
    ssum += w2[p * HPG + o] * v;
  }
  float scr = 1.f / (1.f + expf(-ssum));
  float zs = scr;
  #pragma unroll
  for (int m = 1; m < 64; m <<= 1) zs += __shfl_xor(zs, m, 64);
  float mv = scr; int mi = l;
  #pragma unroll
  for (int m = 1; m < 64; m <<= 1) {
    float ov = __shfl_xor(mv, m, 64);
    int   oi = __shfl_xor(mi, m, 64);
    if (ov > mv || (ov == mv && oi < mi)) { mv = ov; mi = oi; }
  }
  if (l == 0) { z[p * N + n] = zs; mi_out[n * P + p] = mi; }
  score[((size_t)n * P + p) * S + l] = scr;
}

// ============ K3b: y[p][n][i] = sum_s x[n,s,i,p]*score[n,p,s], raw input ====
__global__ __launch_bounds__(256) void k3b_y(
    const float* __restrict__ tf, const float* __restrict__ ts,
    const float* __restrict__ tl, const float* __restrict__ score,
    const int* __restrict__ mi, float* __restrict__ y,
    float* __restrict__ out_spf)
{
  int n = blockIdx.x, chunk = blockIdx.y;
  int z = chunk >> 2, c0 = (chunk & 3) * 32;
  const float* src = (z == 0) ? tf : (z == 1) ? ts : tl;
  int t = threadIdx.x;
  int p = t & 31, cl = t >> 5;
  __shared__ float sc_lds[S * P];   // [s][p]
  __shared__ int mi_lds[P];
  #pragma unroll
  for (int j = 0; j < 8; ++j) {
    int e = t + 256 * j;
    int s2 = e >> 5, pp = e & 31;
    sc_lds[s2 * P + pp] = score[((size_t)n * P + pp) * S + s2];
  }
  if (t < P) mi_lds[t] = mi[n * P + t];
  __syncthreads();
  int mymi = mi_lds[p];
  const float* base = src + (size_t)n * S * C * P + (size_t)(c0 + cl) * P + p;
  float acc[4] = {0.f, 0.f, 0.f, 0.f};
  float sel[4] = {0.f, 0.f, 0.f, 0.f};
  #pragma unroll 8
  for (int s = 0; s < S; ++s) {
    float scv = sc_lds[s * P + p];
    #pragma unroll
    for (int j = 0; j < 4; ++j) {
      float v = base[(size_t)s * C * P + j * 8 * P];
      acc[j] += v * scv;
      sel[j] = (s == mymi) ? v : sel[j];
    }
  }
  float* yp = y + ((size_t)p * N + n) * C3 + z * C + c0 + cl;
  #pragma unroll
  for (int j = 0; j < 4; ++j) yp[j * 8] = acc[j];
  if (z == 0) {
    float* sp = out_spf + ((size_t)p * N + n) * C + c0 + cl;
    #pragma unroll
    for (int j = 0; j < 4; ++j) sp[j * 8] = sel[j];
  }
}

// ============ K4: wpv = (wd . y)/Z, BN over n, write wpv + pf[p][c][n] ============
__global__ __launch_bounds__(256) void k4_wpv(
    const float* __restrict__ y, const float* __restrict__ z,
    const float* __restrict__ wd, const float* __restrict__ g,
    const float* __restrict__ b, float* __restrict__ out_wpv,
    float* __restrict__ pf)
{
  int p   = blockIdx.x;
  int cch = blockIdx.y;             // 0..7
  int t = threadIdx.x;
  int n = t & 63, cg = t >> 6;
  int cbase = cch * 16 + cg * 4;
  __shared__ float ych[96][66];     // i-major, stride 66 -> 2-way (free)
  float acc[4] = {0.f, 0.f, 0.f, 0.f};
  const float* yp  = y  + (size_t)p * N * C3;
  const float* wdp = wd + (size_t)p * C * C3;
  for (int ch = 0; ch < 4; ++ch) {
    __syncthreads();
    #pragma unroll
    for (int j = 0; j < 24; ++j) {
      int e = t + 256 * j;
      int i = e % 96, nn = e / 96;
      ych[i][nn] = yp[nn * C3 + ch * 96 + i];
    }
    __syncthreads();
    #pragma unroll
    for (int sub = 0; sub < 4; ++sub) {
      float yr[24];
      #pragma unroll
      for (int kk = 0; kk < 24; ++kk) yr[kk] = ych[sub * 24 + kk][n];
      int ibase = ch * 96 + sub * 24;
      #pragma unroll
      for (int cl = 0; cl < 4; ++cl) {
        const float4* w4 = (const float4*)(wdp + (size_t)(cbase + cl) * C3 + ibase);
        float a = 0.f;
        #pragma unroll
        for (int q = 0; q < 6; ++q) {
          float4 wv = w4[q];
          a += yr[q*4+0] * wv.x + yr[q*4+1] * wv.y
             + yr[q*4+2] * wv.z + yr[q*4+3] * wv.w;
        }
        acc[cl] += a;
      }
    }
  }
  float zinv = 1.f / z[p * N + n];
  #pragma unroll
  for (int cl = 0; cl < 4; ++cl) acc[cl] *= zinv;
  #pragma unroll
  for (int cl = 0; cl < 4; ++cl) {
    float v = acc[cl];
    float s = v, q = v * v;
    #pragma unroll
    for (int m = 1; m < 64; m <<= 1) {
      s += __shfl_xor(s, m, 64);
      q += __shfl_xor(q, m, 64);
    }
    float mu  = s * (1.f / 64.f);
    float var = q * (1.f / 64.f) - mu * mu;
    int c = cbase + cl;
    float sc = g[p * C + c] * rsqrtf(var + EPSV);
    float sh = b[p * C + c] - mu * sc;
    pf[((size_t)p * C + c) * N + n] = v * sc + sh;   // coalesced over n
  }
  float4 wout = make_float4(acc[0], acc[1], acc[2], acc[3]);
  *(float4*)(out_wpv + ((size_t)p * N + n) * C + cbase) = wout;
}

// ============ K5: part_classification[p][n][k] = sum_c pf[p][c][n]*fc[c][k] ============
__global__ __launch_bounds__(256) void k5_fc(
    const float* __restrict__ pf, const float* __restrict__ fc,
    float* __restrict__ out0)
{
  int kt = blockIdx.x;   // 0..3
  int p  = blockIdx.y;
  int n0 = blockIdx.z * 16;
  int t = threadIdx.x;
  int k = kt * 256 + t;
  bool ok = k < KCLS;
  int kk = ok ? k : (KCLS - 1);
  float acc[16];
  #pragma unroll
  for (int j = 0; j < 16; ++j) acc[j] = 0.f;
  for (int c = 0; c < C; ++c) {
    float fv = fc[c * KCLS + kk];
    const float4* row4 = (const float4*)(pf + ((size_t)p * C + c) * N + n0);
    #pragma unroll
    for (int j4 = 0; j4 < 4; ++j4) {
      float4 r = row4[j4];   // wave-uniform -> scalar loads
      acc[j4*4+0] += r.x * fv; acc[j4*4+1] += r.y * fv;
      acc[j4*4+2] += r.z * fv; acc[j4*4+3] += r.w * fv;
    }
  }
  if (ok) {
    #pragma unroll 4
    for (int j = 0; j < 16; ++j)
      out0[(size_t)(p * N + n0 + j) * KCLS + k] = acc[j];
  }
}

extern "C" void kernel_launch(void* const* d_in, const int* in_sizes, int n_in,
                              void* d_out, int out_size, void* d_ws, size_t ws_size,
                              hipStream_t stream)
{
  const float* tf = (const float*)d_in[0];
  const float* ts = (const float*)d_in[1];
  const float* tl = (const float*)d_in[2];
  const float* w1 = (const float*)d_in[3];
  const float* g1 = (const float*)d_in[4];
  const float* b1 = (const float*)d_in[5];
  const float* w2 = (const float*)d_in[6];
  const float* wd = (const float*)d_in[7];
  const float* g  = (const float*)d_in[8];
  const float* b  = (const float*)d_in[9];
  const float* fc = (const float*)d_in[10];

  float* ws   = (float*)d_ws;
  float* h    = ws + WS_H;
  float* w1z  = ws + WS_W1Z;
  float* bnpT = ws + WS_BNP;
  float* bnss = ws + WS_BNSS;
  float* y    = ws + WS_Y;
  float* z    = ws + WS_Z;
  float* pf   = ws + WS_PF;
  float* sc   = ws + WS_SC;
  int*   mi   = (int*)(ws + WS_MI);

  float* out0 = (float*)d_out;         // part_classification (P,N,K)
  float* out1 = out0 + P * N * KCLS;   // weighted_part_vector (P,N,C)
  float* out2 = out1 + P * N * C;      // selected_part_feature (P,N,C)

  k0w_w1z<<<384, 256, 0, stream>>>(w1, w1z);
  k01_h<<<dim3(64, 8), 256, 0, stream>>>(tf, ts, tl, w1z, h, bnpT);
  k2_bnstat<<<96, 256, 0, stream>>>(bnpT, g1, b1, bnss);
  k3a_score<<<dim3(64, 8), 256, 0, stream>>>(h, bnss, w2, sc, z, mi);
  k3b_y<<<dim3(64, 12), 256, 0, stream>>>(tf, ts, tl, sc, mi, y, out2);
  k4_wpv<<<dim3(32, 8), 256, 0, stream>>>(y, z, wd, g, b, out1, pf);
  k5_fc<<<dim3(4, 32, 4), 256, 0, stream>>>(pf, fc, out0);
}